// Round 1
// baseline (1044.950 us; speedup 1.0000x reference)
//
#include <hip/hip_runtime.h>
#include <math.h>

#define N_NODES 50000
#define N_EDGES 800000
#define NPAIRS  (N_EDGES / 2)

// ---------------------------------------------------------------------------
// Kernel 1: per-node precompute.
//   AB[n][0:128]   = x[n] @ W1[0:128, :]      (contribution of x_src)
//   AB[n][128:256] = x[n] @ W1[128:256, :]    (contribution of x_dst)
// Thread c owns output column c; its 128-float W column lives in registers.
// ---------------------------------------------------------------------------
__global__ __launch_bounds__(256) void node_precompute_kernel(
    const float* __restrict__ x, const float* __restrict__ W1,
    float* __restrict__ AB) {
  __shared__ float xrow[128];
  const int c = threadIdx.x;

  // W'[k][c] = (c < 128) ? W1[k][c] : W1[128+k][c-128]
  const float* Wbase = (c < 128) ? (W1 + c) : (W1 + 128 * 128 + (c - 128));
  float w[128];
#pragma unroll
  for (int k = 0; k < 128; ++k) w[k] = Wbase[k * 128];

  for (int n = blockIdx.x; n < N_NODES; n += gridDim.x) {
    __syncthreads();
    if (c < 128) xrow[c] = x[n * 128 + c];
    __syncthreads();
    float acc = 0.f;
    const float4* x4 = (const float4*)xrow;
#pragma unroll
    for (int q = 0; q < 32; ++q) {
      float4 v = x4[q];
      acc = fmaf(v.x, w[4 * q + 0], acc);
      acc = fmaf(v.y, w[4 * q + 1], acc);
      acc = fmaf(v.z, w[4 * q + 2], acc);
      acc = fmaf(v.w, w[4 * q + 3], acc);
    }
    AB[n * 256 + c] = acc;
  }
}

// ---------------------------------------------------------------------------
// Kernel 2: per-edge fused kernel. 256 threads = 2 edges x 128 threads.
// Thread j owns output column j of its edge:
//   h    = A[src][j] + B[dst][j] + b1[j] + ea . W1e[:,j]
//   base = b_proj[j] + ea . W_proj[:,j]
//   gate = sigmoid( sum_j gelu(h_j) * W2[j] + b2 )   (cross-thread reduce)
//   out[e][j] = base * gate
// W columns (62 floats) live in registers, loaded once per block.
// ---------------------------------------------------------------------------
__global__ __launch_bounds__(256) void edge_kernel(
    const float* __restrict__ edge_attr, const int* __restrict__ edge_index,
    const float* __restrict__ AB,
    const float* __restrict__ W_proj, const float* __restrict__ b_proj,
    const float* __restrict__ W1, const float* __restrict__ b1,
    const float* __restrict__ W2, const float* __restrict__ b2,
    float* __restrict__ out) {
  __shared__ float ea[2][32];   // padded 31 -> 32 for aligned float4 reads
  __shared__ float red[4];

  const int t = threadIdx.x;
  const int s = t >> 7;        // which of the 2 edges in this block-iter
  const int j = t & 127;       // output column
  const int wid = t >> 6;      // wave id 0..3 (waves 0,1 -> s=0; 2,3 -> s=1)

  float wpr[31], w1r[31];
#pragma unroll
  for (int k = 0; k < 31; ++k) {
    wpr[k] = W_proj[k * 128 + j];
    w1r[k] = W1[(256 + k) * 128 + j];
  }
  const float bpj = b_proj[j];
  const float b1j = b1[j];
  const float w2j = W2[j];
  const float b2v = b2[0];

  const int* __restrict__ srcp = edge_index;
  const int* __restrict__ dstp = edge_index + N_EDGES;

  for (int pair = blockIdx.x; pair < NPAIRS; pair += gridDim.x) {
    const int e = pair * 2 + s;

    __syncthreads();  // protect ea from previous iteration's readers
    if (t < 62) {     // 62 consecutive floats cover both edges' attr rows
      const int ss = (t >= 31);
      ea[ss][t - 31 * ss] = edge_attr[pair * 62 + t];
    }
    __syncthreads();

    const int src = srcp[e];
    const int dst = dstp[e];
    float h = AB[src * 256 + j] + AB[dst * 256 + 128 + j] + b1j;
    float base = bpj;

    const float4* ea4 = (const float4*)ea[s];
#pragma unroll
    for (int q = 0; q < 8; ++q) {
      const float4 v = ea4[q];
      const int k0 = 4 * q;
      h = fmaf(v.x, w1r[k0], h);
      base = fmaf(v.x, wpr[k0], base);
      if (k0 + 1 < 31) { h = fmaf(v.y, w1r[k0 + 1], h); base = fmaf(v.y, wpr[k0 + 1], base); }
      if (k0 + 2 < 31) { h = fmaf(v.z, w1r[k0 + 2], h); base = fmaf(v.z, wpr[k0 + 2], base); }
      if (k0 + 3 < 31) { h = fmaf(v.w, w1r[k0 + 3], h); base = fmaf(v.w, wpr[k0 + 3], base); }
    }

    // gelu, tanh approximation (JAX default approximate=True)
    const float u = 0.7978845608028654f * (h + 0.044715f * h * h * h);
    const float th = 1.f - 2.f / (__expf(2.f * u) + 1.f);
    const float g = 0.5f * h * (1.f + th);

    // gate logit: reduce g*W2[j] over this edge's 128 threads (2 waves)
    float r = g * w2j;
#pragma unroll
    for (int off = 32; off > 0; off >>= 1) r += __shfl_xor(r, off);
    if ((t & 63) == 0) red[wid] = r;
    __syncthreads();
    const float logit = red[2 * s] + red[2 * s + 1] + b2v;
    const float gate = 1.f / (1.f + __expf(-logit));

    out[(long)e * 128 + j] = base * gate;
  }
}

extern "C" void kernel_launch(void* const* d_in, const int* in_sizes, int n_in,
                              void* d_out, int out_size, void* d_ws, size_t ws_size,
                              hipStream_t stream) {
  const float* x         = (const float*)d_in[0];
  const float* edge_attr = (const float*)d_in[1];
  const int*   edge_index= (const int*)d_in[2];
  const float* W_proj    = (const float*)d_in[3];
  const float* b_proj    = (const float*)d_in[4];
  const float* W1        = (const float*)d_in[5];
  const float* b1        = (const float*)d_in[6];
  const float* W2        = (const float*)d_in[7];
  const float* b2        = (const float*)d_in[8];
  float* out = (float*)d_out;
  float* AB  = (float*)d_ws;   // 50000 * 256 floats = 51.2 MB

  hipLaunchKernelGGL(node_precompute_kernel, dim3(1024), dim3(256), 0, stream,
                     x, W1, AB);
  hipLaunchKernelGGL(edge_kernel, dim3(2048), dim3(256), 0, stream,
                     edge_attr, edge_index, AB, W_proj, b_proj, W1, b1, W2, b2,
                     out);
}

// Round 2
// 849.217 us; speedup vs baseline: 1.2305x; 1.2305x over previous
//
#include <hip/hip_runtime.h>
#include <math.h>

#define N_NODES 50000
#define N_EDGES 800000

__device__ __forceinline__ float gelu_f(float h) {
  // jax.nn.gelu approximate=True (tanh form), tanh via exp
  const float u = 0.7978845608028654f * (h + 0.044715f * h * h * h);
  const float th = 1.f - 2.f / (__expf(2.f * u) + 1.f);
  return 0.5f * h * (1.f + th);
}

// ---------------------------------------------------------------------------
// Kernel 1: per-node precompute.
//   AB[n][0:128]   = x[n] @ W1[0:128, :]      (x_src contribution)
//   AB[n][128:256] = x[n] @ W1[128:256, :]    (x_dst contribution)
// ---------------------------------------------------------------------------
__global__ __launch_bounds__(256) void node_precompute_kernel(
    const float* __restrict__ x, const float* __restrict__ W1,
    float* __restrict__ AB) {
  __shared__ float xrow[128];
  const int c = threadIdx.x;

  const float* Wbase = (c < 128) ? (W1 + c) : (W1 + 128 * 128 + (c - 128));
  float w[128];
#pragma unroll
  for (int k = 0; k < 128; ++k) w[k] = Wbase[k * 128];

  for (int n = blockIdx.x; n < N_NODES; n += gridDim.x) {
    __syncthreads();
    if (c < 128) xrow[c] = x[n * 128 + c];
    __syncthreads();
    float acc = 0.f;
    const float4* x4 = (const float4*)xrow;
#pragma unroll
    for (int q = 0; q < 32; ++q) {
      float4 v = x4[q];
      acc = fmaf(v.x, w[4 * q + 0], acc);
      acc = fmaf(v.y, w[4 * q + 1], acc);
      acc = fmaf(v.z, w[4 * q + 2], acc);
      acc = fmaf(v.w, w[4 * q + 3], acc);
    }
    AB[n * 256 + c] = acc;
  }
}

// ---------------------------------------------------------------------------
// Kernel 2: gate. One wave per edge, zero barriers, zero LDS.
// Lane l owns hidden columns 2l, 2l+1. ea lives one-element-per-lane and is
// broadcast with compile-time __shfl (v_readlane). Wave shfl_xor reduce.
// ---------------------------------------------------------------------------
__global__ __launch_bounds__(256) void gate_kernel(
    const float* __restrict__ edge_attr, const int* __restrict__ edge_index,
    const float* __restrict__ AB, const float* __restrict__ W1,
    const float* __restrict__ b1, const float* __restrict__ W2,
    const float* __restrict__ b2, float* __restrict__ gate) {
  const int l = threadIdx.x & 63;
  const int wv = threadIdx.x >> 6;
  const int j0 = 2 * l;

  float w1r[31][2];
#pragma unroll
  for (int k = 0; k < 31; ++k) {
    w1r[k][0] = W1[(256 + k) * 128 + j0];
    w1r[k][1] = W1[(256 + k) * 128 + j0 + 1];
  }
  const float b10 = b1[j0], b11 = b1[j0 + 1];
  const float w20 = W2[j0], w21 = W2[j0 + 1];
  const float b2v = b2[0];

  const int stride = gridDim.x * 4;
  for (int e = blockIdx.x * 4 + wv; e < N_EDGES; e += stride) {
    const int src = edge_index[e];
    const int dst = edge_index[N_EDGES + e];
    const float eav = (l < 31) ? edge_attr[e * 31 + l] : 0.f;
    const float2 av = *(const float2*)(AB + src * 256 + j0);
    const float2 bv = *(const float2*)(AB + dst * 256 + 128 + j0);

    float h0 = av.x + bv.x + b10;
    float h1 = av.y + bv.y + b11;
#pragma unroll
    for (int k = 0; k < 31; ++k) {
      const float v = __shfl(eav, k);
      h0 = fmaf(v, w1r[k][0], h0);
      h1 = fmaf(v, w1r[k][1], h1);
    }

    float r = fmaf(gelu_f(h0), w20, gelu_f(h1) * w21);
#pragma unroll
    for (int off = 32; off > 0; off >>= 1) r += __shfl_xor(r, off);

    if (l == 0) gate[e] = 1.f / (1.f + __expf(-(r + b2v)));
  }
}

// ---------------------------------------------------------------------------
// Kernel 3: output. One wave per edge, zero barriers, zero LDS.
// out[e][j] = (b_proj[j] + ea . W_proj[:,j]) * gate[e], float2 stores.
// ---------------------------------------------------------------------------
__global__ __launch_bounds__(256) void out_kernel(
    const float* __restrict__ edge_attr, const float* __restrict__ gate,
    const float* __restrict__ W_proj, const float* __restrict__ b_proj,
    float* __restrict__ out) {
  const int l = threadIdx.x & 63;
  const int wv = threadIdx.x >> 6;
  const int j0 = 2 * l;

  float wpr[31][2];
#pragma unroll
  for (int k = 0; k < 31; ++k) {
    wpr[k][0] = W_proj[k * 128 + j0];
    wpr[k][1] = W_proj[k * 128 + j0 + 1];
  }
  const float bp0 = b_proj[j0], bp1 = b_proj[j0 + 1];

  const int stride = gridDim.x * 4;
  for (int e = blockIdx.x * 4 + wv; e < N_EDGES; e += stride) {
    const float eav = (l < 31) ? edge_attr[e * 31 + l] : 0.f;
    const float g = gate[e];   // wave-uniform broadcast load

    float a0 = bp0, a1 = bp1;
#pragma unroll
    for (int k = 0; k < 31; ++k) {
      const float v = __shfl(eav, k);
      a0 = fmaf(v, wpr[k][0], a0);
      a1 = fmaf(v, wpr[k][1], a1);
    }

    float2 o;
    o.x = a0 * g;
    o.y = a1 * g;
    *(float2*)(out + (long)e * 128 + j0) = o;
  }
}

extern "C" void kernel_launch(void* const* d_in, const int* in_sizes, int n_in,
                              void* d_out, int out_size, void* d_ws, size_t ws_size,
                              hipStream_t stream) {
  const float* x          = (const float*)d_in[0];
  const float* edge_attr  = (const float*)d_in[1];
  const int*   edge_index = (const int*)d_in[2];
  const float* W_proj     = (const float*)d_in[3];
  const float* b_proj     = (const float*)d_in[4];
  const float* W1         = (const float*)d_in[5];
  const float* b1         = (const float*)d_in[6];
  const float* W2         = (const float*)d_in[7];
  const float* b2         = (const float*)d_in[8];
  float* out  = (float*)d_out;
  float* AB   = (float*)d_ws;                        // 50000*256 f32 = 51.2 MB
  float* gate = (float*)d_ws + (size_t)N_NODES * 256; // 800000 f32 = 3.2 MB

  hipLaunchKernelGGL(node_precompute_kernel, dim3(1024), dim3(256), 0, stream,
                     x, W1, AB);
  hipLaunchKernelGGL(gate_kernel, dim3(2048), dim3(256), 0, stream,
                     edge_attr, edge_index, AB, W1, b1, W2, b2, gate);
  hipLaunchKernelGGL(out_kernel, dim3(2048), dim3(256), 0, stream,
                     edge_attr, gate, W_proj, b_proj, out);
}

// Round 3
// 606.529 us; speedup vs baseline: 1.7228x; 1.4001x over previous
//
#include <hip/hip_runtime.h>
#include <math.h>

#define N_NODES 50000
#define N_EDGES 800000

__device__ __forceinline__ float gelu_f(float h) {
  // jax.nn.gelu approximate=True (tanh form), tanh via exp
  const float u = 0.7978845608028654f * (h + 0.044715f * h * h * h);
  const float th = 1.f - 2.f / (__expf(2.f * u) + 1.f);
  return 0.5f * h * (1.f + th);
}

// ---------------------------------------------------------------------------
// Kernel 1: per-node precompute (no LDS, no barriers).
//   AB[n][0:128]   = x[n] @ W1[0:128, :]      (x_src contribution)
//   AB[n][128:256] = x[n] @ W1[128:256, :]    (x_dst contribution)
// Row pointer is wave-uniform -> x row rides the scalar cache (s_load).
// Weight column stays in VGPRs (launch_bounds min-waves=1 frees the budget).
// ---------------------------------------------------------------------------
__global__ __launch_bounds__(256, 1) void node_precompute_kernel(
    const float* __restrict__ x, const float* __restrict__ W1,
    float* __restrict__ AB) {
  const int c = threadIdx.x;
  const float* Wbase = (c < 128) ? (W1 + c) : (W1 + 128 * 128 + (c - 128));
  float w[128];
#pragma unroll
  for (int k = 0; k < 128; ++k) w[k] = Wbase[k * 128];

  for (int n0 = blockIdx.x; n0 < N_NODES; n0 += gridDim.x) {
    const int n = __builtin_amdgcn_readfirstlane(n0);
    const float* __restrict__ xr = x + (size_t)n * 128;  // uniform pointer
    float acc = 0.f;
#pragma unroll
    for (int k = 0; k < 128; ++k) acc = fmaf(xr[k], w[k], acc);
    AB[(size_t)n * 256 + c] = acc;
  }
}

// ---------------------------------------------------------------------------
// Kernel 2: fused edge kernel. One wave per edge, zero barriers, zero LDS.
// Lane l owns output columns j0=2l, j0+1. The 31-float edge_attr row and the
// edge indices are wave-uniform -> scalar loads (SGPR operands feed v_fmac).
//   h_j    = A[src][j] + B[dst][j] + b1[j] + ea . W1e[:,j]
//   base_j = b_proj[j] + ea . W_proj[:,j]
//   gate   = sigmoid( sum_j gelu(h_j)*W2[j] + b2 )   (6-step wave reduce)
//   out[e][j] = base_j * gate
// ---------------------------------------------------------------------------
__global__ __launch_bounds__(256, 1) void edge_kernel(
    const float* __restrict__ edge_attr, const int* __restrict__ edge_index,
    const float* __restrict__ AB,
    const float* __restrict__ W_proj, const float* __restrict__ b_proj,
    const float* __restrict__ W1, const float* __restrict__ b1,
    const float* __restrict__ W2, const float* __restrict__ b2,
    float* __restrict__ out) {
  const int l = threadIdx.x & 63;
  const int wv = threadIdx.x >> 6;
  const int j0 = 2 * l;

  // Weight columns live in VGPRs for the whole kernel: 31 float2 each.
  float2 w1r[31], wpr[31];
#pragma unroll
  for (int k = 0; k < 31; ++k) {
    w1r[k] = *(const float2*)(W1 + (size_t)(256 + k) * 128 + j0);
    wpr[k] = *(const float2*)(W_proj + (size_t)k * 128 + j0);
  }
  const float2 b1v = *(const float2*)(b1 + j0);
  const float2 bpv = *(const float2*)(b_proj + j0);
  const float2 w2v = *(const float2*)(W2 + j0);
  const float b2v = b2[0];

  const int nwaves = gridDim.x * 4;
  const int wid = blockIdx.x * 4 + wv;

  for (int e0 = wid; e0 < N_EDGES; e0 += nwaves) {
    const int e = __builtin_amdgcn_readfirstlane(e0);
    const int src = edge_index[e];                 // uniform -> s_load
    const int dst = edge_index[N_EDGES + e];       // uniform -> s_load
    const float* __restrict__ ea = edge_attr + (size_t)e * 31;  // uniform row

    const float2 av = *(const float2*)(AB + (size_t)src * 256 + j0);
    const float2 bv = *(const float2*)(AB + (size_t)dst * 256 + 128 + j0);

    float h0 = av.x + bv.x + b1v.x;
    float h1 = av.y + bv.y + b1v.y;
    float a0 = bpv.x, a1 = bpv.y;
#pragma unroll
    for (int k = 0; k < 31; ++k) {
      const float v = ea[k];                       // uniform -> SGPR operand
      h0 = fmaf(v, w1r[k].x, h0);
      h1 = fmaf(v, w1r[k].y, h1);
      a0 = fmaf(v, wpr[k].x, a0);
      a1 = fmaf(v, wpr[k].y, a1);
    }

    // gate logit: reduce gelu(h)*W2 over the 64 lanes (128 columns)
    float r = fmaf(gelu_f(h0), w2v.x, gelu_f(h1) * w2v.y);
#pragma unroll
    for (int off = 32; off > 0; off >>= 1) r += __shfl_xor(r, off);
    const float gate = 1.f / (1.f + __expf(-(r + b2v)));

    float2 o;
    o.x = a0 * gate;
    o.y = a1 * gate;
    *(float2*)(out + (size_t)e * 128 + j0) = o;
  }
}

extern "C" void kernel_launch(void* const* d_in, const int* in_sizes, int n_in,
                              void* d_out, int out_size, void* d_ws, size_t ws_size,
                              hipStream_t stream) {
  const float* x          = (const float*)d_in[0];
  const float* edge_attr  = (const float*)d_in[1];
  const int*   edge_index = (const int*)d_in[2];
  const float* W_proj     = (const float*)d_in[3];
  const float* b_proj     = (const float*)d_in[4];
  const float* W1         = (const float*)d_in[5];
  const float* b1         = (const float*)d_in[6];
  const float* W2         = (const float*)d_in[7];
  const float* b2         = (const float*)d_in[8];
  float* out = (float*)d_out;
  float* AB  = (float*)d_ws;   // 50000*256 f32 = 51.2 MB

  hipLaunchKernelGGL(node_precompute_kernel, dim3(2048), dim3(256), 0, stream,
                     x, W1, AB);
  hipLaunchKernelGGL(edge_kernel, dim3(2048), dim3(256), 0, stream,
                     edge_attr, edge_index, AB, W_proj, b_proj, W1, b1, W2, b2,
                     out);
}

// Round 4
// 278.772 us; speedup vs baseline: 3.7484x; 2.1757x over previous
//
#include <hip/hip_runtime.h>
#include <math.h>

#define N_NODES 50000
#define N_EDGES 800000

typedef __attribute__((ext_vector_type(8))) short bf16x8;
typedef __attribute__((ext_vector_type(4))) float f32x4;

// round-to-nearest-even float -> bf16 (matches HW/numpy for normal inputs)
__device__ __forceinline__ short f2bf(float f) {
  union { float f; unsigned u; } v; v.f = f;
  unsigned r = v.u + 0x7FFFu + ((v.u >> 16) & 1u);
  return (short)(r >> 16);
}

// tanh-gelu (jax approximate=True): gelu(h) = h*e/(e+1), e = exp(2u),
// u = 0.7978845608*(h + 0.044715 h^3). Overflow-safe (e=inf -> gelu=h).
__device__ __forceinline__ float gelu_f(float h) {
  const float m1 = h * h;
  const float t2u = h * fmaf(0.07135481f, m1, 1.5957691f);
  const float e = __expf(t2u);
  const float rc = __builtin_amdgcn_rcpf(1.f + e);
  return h - h * rc;
}

#define PIN(v) asm volatile("" : "+v"(v))

// ---------------------------------------------------------------------------
// Kernel 1: AB[n][c] = x[n] @ Wab[:,c] + 0.5*b1[c mod 128]
//   Wab[k][c] = (c<128) ? W1[k][c] : W1[128+k][c-128]
// MFMA 16x16x32_bf16, M=cols, N=16 nodes, K=128 (4 k-steps).
// Each wave owns a 64-col strip (4 col-blocks) and loops node-tiles.
// Fragment maps (16x16x32): A[m][k]: m=lane&15, k=(lane>>4)*8+t
//                           B[k][n]: n=lane&15, k=(lane>>4)*8+t
//                           D[m][n]: n=lane&15, m=(lane>>4)*4+i   (verified)
// ---------------------------------------------------------------------------
__global__ __launch_bounds__(256) void node_kernel(
    const float* __restrict__ x, const float* __restrict__ W1,
    const float* __restrict__ b1, float* __restrict__ AB) {
  const int l = threadIdx.x & 63;
  const int wv = threadIdx.x >> 6;
  const int r = l & 15, g4 = l >> 4;

  const int wid = blockIdx.x * 4 + wv;   // 4096 waves
  const int s = wid & 3;                 // col strip: blocks mb = 4s+q

  // weight A-frags (held in regs): wA[q][ks][t] = Wab[ks*32+g4*8+t][16*(4s+q)+r]
  bf16x8 wA[4][4];
#pragma unroll
  for (int q = 0; q < 4; ++q) {
    const int c = 16 * (4 * s + q) + r;
    const float* Wb = (c < 128) ? (W1 + c) : (W1 + 128 * 128 + (c - 128));
#pragma unroll
    for (int ks = 0; ks < 4; ++ks) {
#pragma unroll
      for (int t = 0; t < 8; ++t)
        wA[q][ks][t] = f2bf(Wb[(size_t)(ks * 32 + g4 * 8 + t) * 128]);
      PIN(wA[q][ks]);
    }
  }
  // bias float4 per q: b1[(16*(4s+q)+g4*4 .. +3) mod 128]
  float4 bv[4];
#pragma unroll
  for (int q = 0; q < 4; ++q)
    bv[q] = *(const float4*)(b1 + ((16 * (4 * s + q) + g4 * 4) & 127));

  for (int t0 = wid >> 2; t0 < (N_NODES / 16); t0 += 1024) {
    const int n0 = t0 * 16;
    // x B-frags per k-step: b[t] = x[n0+r][ks*32+g4*8+t]
    f32x4 acc[4] = {{0,0,0,0},{0,0,0,0},{0,0,0,0},{0,0,0,0}};
#pragma unroll
    for (int ks = 0; ks < 4; ++ks) {
      const float* xr = x + (size_t)(n0 + r) * 128 + ks * 32 + g4 * 8;
      const float4 x0 = *(const float4*)xr;
      const float4 x1 = *(const float4*)(xr + 4);
      bf16x8 xb;
      xb[0] = f2bf(x0.x); xb[1] = f2bf(x0.y); xb[2] = f2bf(x0.z); xb[3] = f2bf(x0.w);
      xb[4] = f2bf(x1.x); xb[5] = f2bf(x1.y); xb[6] = f2bf(x1.z); xb[7] = f2bf(x1.w);
#pragma unroll
      for (int q = 0; q < 4; ++q)
        acc[q] = __builtin_amdgcn_mfma_f32_16x16x32_bf16(wA[q][ks], xb, acc[q], 0, 0, 0);
    }
#pragma unroll
    for (int q = 0; q < 4; ++q) {
      float4 o;
      o.x = acc[q][0] + 0.5f * bv[q].x;
      o.y = acc[q][1] + 0.5f * bv[q].y;
      o.z = acc[q][2] + 0.5f * bv[q].z;
      o.w = acc[q][3] + 0.5f * bv[q].w;
      *(float4*)(AB + (size_t)(n0 + r) * 256 + 16 * (4 * s + q) + g4 * 4) = o;
    }
  }
}

// ---------------------------------------------------------------------------
// Kernel 2: fused edge kernel. One wave = 16 edges, MFMA for both ea-GEMMs.
//   h[j][e]    = AB[src][j] + AB[dst][128+j] (+b1 baked) + (W1e^T @ ea^T)
//   base[j][e] = (W_proj^T @ ea^T)  (+ b_proj in epilogue)
//   gate[e]    = sigmoid( sum_j gelu(h)*W2[j] + b2 )
//   out[e][j]  = (base + b_proj) * gate
// M=cols (8 blocks of 16), N=16 edges, K=32 (31 padded).
// ---------------------------------------------------------------------------
__global__ __launch_bounds__(256) void edge_kernel(
    const float* __restrict__ edge_attr, const int* __restrict__ edge_index,
    const float* __restrict__ AB,
    const float* __restrict__ W_proj, const float* __restrict__ b_proj,
    const float* __restrict__ W1,
    const float* __restrict__ W2, const float* __restrict__ b2,
    float* __restrict__ out) {
  const int l = threadIdx.x & 63;
  const int wv = threadIdx.x >> 6;
  const int r = l & 15, g4 = l >> 4;

  // weight A-frags, pinned resident: [t] = W[g4*8+t][16*mb + r], k=31 pad -> 0
  bf16x8 wP[8], wH[8];
#pragma unroll
  for (int mb = 0; mb < 8; ++mb) {
    const int c = 16 * mb + r;
    bf16x8 p, h;
#pragma unroll
    for (int t = 0; t < 8; ++t) {
      const int kk = g4 * 8 + t;
      p[t] = (kk < 31) ? f2bf(W_proj[(size_t)kk * 128 + c]) : (short)0;
      h[t] = (kk < 31) ? f2bf(W1[(size_t)(256 + kk) * 128 + c]) : (short)0;
    }
    wP[mb] = p; wH[mb] = h;
    PIN(wP[mb]); PIN(wH[mb]);
  }
  const float b2v = b2[0];

  const int nwaves = gridDim.x * 4;
  for (int tile = blockIdx.x * 4 + wv; tile < (N_EDGES / 16); tile += nwaves) {
    const int e = tile * 16 + r;             // this lane's edge
    const int src = edge_index[e];
    const int dst = edge_index[N_EDGES + e];

    // ea B-frag: b[t] = ea[e][g4*8+t], k=31 pad -> 0
    const float* ear = edge_attr + (size_t)e * 31 + g4 * 8;
    bf16x8 eb;
#pragma unroll
    for (int t = 0; t < 8; ++t) {
      const int kk = g4 * 8 + t;
      eb[t] = (kk < 31) ? f2bf(ear[t]) : (short)0;
    }

    // gathers init the h accumulator (fp32, b1 already baked into AB)
    const float* arow = AB + (size_t)src * 256 + g4 * 4;
    const float* brow = AB + (size_t)dst * 256 + 128 + g4 * 4;
    f32x4 acch[8], accb[8];
#pragma unroll
    for (int mb = 0; mb < 8; ++mb) {
      const float4 ga = *(const float4*)(arow + 16 * mb);
      const float4 gb = *(const float4*)(brow + 16 * mb);
      f32x4 c; c[0] = ga.x + gb.x; c[1] = ga.y + gb.y;
      c[2] = ga.z + gb.z; c[3] = ga.w + gb.w;
      acch[mb] = c;
      accb[mb] = (f32x4){0.f, 0.f, 0.f, 0.f};
    }
#pragma unroll
    for (int mb = 0; mb < 8; ++mb) {
      acch[mb] = __builtin_amdgcn_mfma_f32_16x16x32_bf16(wH[mb], eb, acch[mb], 0, 0, 0);
      accb[mb] = __builtin_amdgcn_mfma_f32_16x16x32_bf16(wP[mb], eb, accb[mb], 0, 0, 0);
    }

    // gate logit: this lane holds cols j=16mb+g4*4+i of edge e
    float lg = 0.f;
#pragma unroll
    for (int mb = 0; mb < 8; ++mb) {
      const float4 w2v = *(const float4*)(W2 + 16 * mb + g4 * 4);
      lg = fmaf(gelu_f(acch[mb][0]), w2v.x, lg);
      lg = fmaf(gelu_f(acch[mb][1]), w2v.y, lg);
      lg = fmaf(gelu_f(acch[mb][2]), w2v.z, lg);
      lg = fmaf(gelu_f(acch[mb][3]), w2v.w, lg);
    }
    lg += __shfl_xor(lg, 16);
    lg += __shfl_xor(lg, 32);
    const float gate = __builtin_amdgcn_rcpf(1.f + __expf(-(lg + b2v)));

    float* orow = out + (size_t)e * 128 + g4 * 4;
#pragma unroll
    for (int mb = 0; mb < 8; ++mb) {
      const float4 bp = *(const float4*)(b_proj + 16 * mb + g4 * 4);
      float4 o;
      o.x = (accb[mb][0] + bp.x) * gate;
      o.y = (accb[mb][1] + bp.y) * gate;
      o.z = (accb[mb][2] + bp.z) * gate;
      o.w = (accb[mb][3] + bp.w) * gate;
      *(float4*)(orow + 16 * mb) = o;
    }
  }
}

extern "C" void kernel_launch(void* const* d_in, const int* in_sizes, int n_in,
                              void* d_out, int out_size, void* d_ws, size_t ws_size,
                              hipStream_t stream) {
  const float* x          = (const float*)d_in[0];
  const float* edge_attr  = (const float*)d_in[1];
  const int*   edge_index = (const int*)d_in[2];
  const float* W_proj     = (const float*)d_in[3];
  const float* b_proj     = (const float*)d_in[4];
  const float* W1         = (const float*)d_in[5];
  const float* b1         = (const float*)d_in[6];
  const float* W2         = (const float*)d_in[7];
  const float* b2         = (const float*)d_in[8];
  float* out = (float*)d_out;
  float* AB  = (float*)d_ws;   // 50000*256 f32 = 51.2 MB

  hipLaunchKernelGGL(node_kernel, dim3(1024), dim3(256), 0, stream,
                     x, W1, b1, AB);
  hipLaunchKernelGGL(edge_kernel, dim3(2048), dim3(256), 0, stream,
                     edge_attr, edge_index, AB, W_proj, b_proj, W1, W2, b2,
                     out);
}